// Round 1
// 816.364 us; speedup vs baseline: 1.8348x; 1.8348x over previous
//
#include <hip/hip_runtime.h>
#include <hip/hip_bf16.h>

#define B_ 4
#define S_ 4096
#define DM 512
#define DH 64

#define NEG_BIG (-3.0e38f)

// ---------------------------------------------------------------------------
// Dtype detector: scans first 2048 uint16 halves of q_in. bf16 N(0,1) data
// has exponent fields ~[96,134]; fp32 data reinterpreted as u16 has random
// exponent fields in ~42% of halves. flag=1 -> inputs are fp32.
// ---------------------------------------------------------------------------
__global__ void detect_kernel(const unsigned short* __restrict__ u,
                              int* __restrict__ flag) {
    __shared__ int cnt;
    if (threadIdx.x == 0) cnt = 0;
    __syncthreads();
    int w = 0;
    #pragma unroll
    for (int k = 0; k < 8; ++k) {
        unsigned short x = u[threadIdx.x * 8 + k];
        int e = (x >> 7) & 0xFF;
        if (e >= 135 || (e > 0 && e <= 95)) ++w;
    }
    atomicAdd(&cnt, w);
    __syncthreads();
    if (threadIdx.x == 0) *flag = (cnt > 64) ? 1 : 0;
}

__device__ __forceinline__ float bf2f(unsigned short u) {
    unsigned int x = ((unsigned int)u) << 16;
    float f;
    __builtin_memcpy(&f, &x, 4);
    return f;
}

// ---------------------------------------------------------------------------
// Projection v2: tiled GEMM. out[row,h] = sum_d x[row,d]*W[h,d] + b[h].
// One block = 64 rows x 64 heads. K chunked by 64.
// LDS: Xs[64 rows][64 k] row-major, Ws[64 k][64 h] TRANSPOSED (so the
// 4-head read is a contiguous float4 -> conflict-free ds_read_b128).
// Thread (tr,tc) = (t>>4, t&15) computes rows tr*4..+3, heads tc*4..+3
// (4x4 register tile, 8 b128 LDS reads per 64 FMAs).
// W is read from global once per block (768 blocks) instead of once per
// row (49152 blocks) as before.
// ---------------------------------------------------------------------------
#define TM 64
#define KC 64
#define LDX 68   // 68*4=272B row stride: rows land in 2 bank-groups -> 2-way (free)
#define LDW 65   // 65 = 1 mod 32: transpose writes spread across all banks

__global__ __launch_bounds__(256) void proj_kernel(
    const void* __restrict__ xq, const void* __restrict__ xk,
    const void* __restrict__ xv,
    const void* __restrict__ Wq, const void* __restrict__ Wk,
    const void* __restrict__ Wv,
    const void* __restrict__ bq, const void* __restrict__ bk,
    const void* __restrict__ bv,
    float* __restrict__ Qo, float* __restrict__ Ko, float* __restrict__ Vo,
    const int* __restrict__ flag)
{
    const int which = blockIdx.y;
    const void* x    = (which == 0) ? xq : (which == 1) ? xk : xv;
    const void* W    = (which == 0) ? Wq : (which == 1) ? Wk : Wv;
    const void* bias = (which == 0) ? bq : (which == 1) ? bk : bv;
    float* out       = (which == 0) ? Qo : (which == 1) ? Ko : Vo;

    const bool f32 = (*flag != 0);
    const int row0 = blockIdx.x * TM;
    const int t    = threadIdx.x;
    const int tr   = t >> 4;   // 0..15 row-group
    const int tc   = t & 15;   // 0..15 head-group

    __shared__ float Xs[TM][LDX];
    __shared__ float Ws[KC][LDW];   // transposed: Ws[k][h]

    float acc[4][4];
    #pragma unroll
    for (int r = 0; r < 4; ++r)
        #pragma unroll
        for (int h = 0; h < 4; ++h) acc[r][h] = 0.f;

    for (int kc = 0; kc < DM; kc += KC) {
        __syncthreads();   // previous chunk's LDS reads complete
        if (f32) {
            const float* xb = (const float*)x;
            #pragma unroll
            for (int jv = 0; jv < 4; ++jv) {
                int lidx = jv * 256 + t;
                int r = lidx >> 4, kq = lidx & 15;
                float4 v = *reinterpret_cast<const float4*>(
                    xb + (size_t)(row0 + r) * DM + kc + kq * 4);
                *reinterpret_cast<float4*>(&Xs[r][kq * 4]) = v;
            }
            const float* wb = (const float*)W;
            #pragma unroll
            for (int jv = 0; jv < 4; ++jv) {
                int lidx = jv * 256 + t;
                int h = lidx >> 4, kq = lidx & 15;
                float4 v = *reinterpret_cast<const float4*>(
                    wb + (size_t)h * DM + kc + kq * 4);
                Ws[kq * 4 + 0][h] = v.x;
                Ws[kq * 4 + 1][h] = v.y;
                Ws[kq * 4 + 2][h] = v.z;
                Ws[kq * 4 + 3][h] = v.w;
            }
        } else {
            const unsigned short* xb = (const unsigned short*)x;
            #pragma unroll
            for (int jv = 0; jv < 4; ++jv) {
                int lidx = jv * 256 + t;
                int r = lidx >> 4, kq = lidx & 15;
                ushort4 u = *reinterpret_cast<const ushort4*>(
                    xb + (size_t)(row0 + r) * DM + kc + kq * 4);
                Xs[r][kq * 4 + 0] = bf2f(u.x);
                Xs[r][kq * 4 + 1] = bf2f(u.y);
                Xs[r][kq * 4 + 2] = bf2f(u.z);
                Xs[r][kq * 4 + 3] = bf2f(u.w);
            }
            const unsigned short* wb = (const unsigned short*)W;
            #pragma unroll
            for (int jv = 0; jv < 4; ++jv) {
                int lidx = jv * 256 + t;
                int h = lidx >> 4, kq = lidx & 15;
                ushort4 u = *reinterpret_cast<const ushort4*>(
                    wb + (size_t)h * DM + kc + kq * 4);
                Ws[kq * 4 + 0][h] = bf2f(u.x);
                Ws[kq * 4 + 1][h] = bf2f(u.y);
                Ws[kq * 4 + 2][h] = bf2f(u.z);
                Ws[kq * 4 + 3][h] = bf2f(u.w);
            }
        }
        __syncthreads();

        #pragma unroll
        for (int k4 = 0; k4 < KC / 4; ++k4) {
            float4 xv4[4], wv4[4];
            #pragma unroll
            for (int r = 0; r < 4; ++r)
                xv4[r] = *reinterpret_cast<const float4*>(&Xs[tr * 4 + r][k4 * 4]);
            #pragma unroll
            for (int j = 0; j < 4; ++j)
                wv4[j] = *reinterpret_cast<const float4*>(&Ws[k4 * 4 + j][tc * 4]);
            #pragma unroll
            for (int r = 0; r < 4; ++r) {
                const float* xp = reinterpret_cast<const float*>(&xv4[r]);
                #pragma unroll
                for (int j = 0; j < 4; ++j) {
                    const float* wp = reinterpret_cast<const float*>(&wv4[j]);
                    float xs = xp[j];
                    #pragma unroll
                    for (int h = 0; h < 4; ++h)
                        acc[r][h] = fmaf(xs, wp[h], acc[r][h]);
                }
            }
        }
    }

    float bs[4];
    #pragma unroll
    for (int h = 0; h < 4; ++h)
        bs[h] = f32 ? ((const float*)bias)[tc * 4 + h]
                    : bf2f(((const unsigned short*)bias)[tc * 4 + h]);

    #pragma unroll
    for (int r = 0; r < 4; ++r) {
        float4 o;
        o.x = acc[r][0] + bs[0];
        o.y = acc[r][1] + bs[1];
        o.z = acc[r][2] + bs[2];
        o.w = acc[r][3] + bs[3];
        *reinterpret_cast<float4*>(
            out + (size_t)(row0 + tr * 4 + r) * DH + tc * 4) = o;
    }
}

// ---------------------------------------------------------------------------
// Flash attention (causal). One block = 64 query rows of one batch.
// 256 threads: thread t -> query row i = t/4, col-group sub = t&3.
// Thread's 16 score cols are j = jj*4 + sub. Online softmax state (m,l)
// replicated across each quad via __shfl_xor. All math finite (no inf-inf).
// Output dtype chosen at runtime via *flag (0=bf16, 1=fp32).
// ---------------------------------------------------------------------------
#define LD 68   // LDS row stride in floats: 272 B, 16B-aligned, +4 banks/row

__global__ __launch_bounds__(256) void flash_kernel(
    const float* __restrict__ Q, const float* __restrict__ K,
    const float* __restrict__ V, void* __restrict__ out,
    const int* __restrict__ flag)
{
    const int qt   = blockIdx.x;       // 0..63
    const int b    = blockIdx.y;       // 0..3
    const int tid  = threadIdx.x;
    const int lane = tid & 63;
    const int i    = tid >> 2;         // query row in tile
    const int sub  = tid & 3;

    __shared__ float Qs[64][LD];
    __shared__ float Ks[64][LD];
    __shared__ float Vs[64][LD];

    const int    qbase     = qt * 64;
    const size_t batch_off = (size_t)b * S_ * DH;

    // load + scale Q tile: thread loads row tid/4, dims (tid&3)*16 .. +16
    {
        const int r  = tid >> 2;
        const int d0 = (tid & 3) * 16;
        const float4* src = reinterpret_cast<const float4*>(
            Q + batch_off + (size_t)(qbase + r) * DH + d0);
        #pragma unroll
        for (int c = 0; c < 4; ++c) {
            float4 f = src[c];
            Qs[r][d0 + c * 4 + 0] = f.x * 0.125f;   // 1/sqrt(64)
            Qs[r][d0 + c * 4 + 1] = f.y * 0.125f;
            Qs[r][d0 + c * 4 + 2] = f.z * 0.125f;
            Qs[r][d0 + c * 4 + 3] = f.w * 0.125f;
        }
    }

    float o[16];
    #pragma unroll
    for (int dd = 0; dd < 16; ++dd) o[dd] = 0.f;
    float m = NEG_BIG;
    float l = 0.f;

    for (int kt = 0; kt <= qt; ++kt) {
        __syncthreads();   // previous tile's reads done (also orders Q fill)
        {
            const int r  = tid >> 2;
            const int d0 = (tid & 3) * 16;
            const size_t goff = batch_off + (size_t)(kt * 64 + r) * DH + d0;
            const float4* ks = reinterpret_cast<const float4*>(K + goff);
            const float4* vs = reinterpret_cast<const float4*>(V + goff);
            #pragma unroll
            for (int c = 0; c < 4; ++c) {
                float4 f = ks[c];
                Ks[r][d0 + c * 4 + 0] = f.x;
                Ks[r][d0 + c * 4 + 1] = f.y;
                Ks[r][d0 + c * 4 + 2] = f.z;
                Ks[r][d0 + c * 4 + 3] = f.w;
                float4 g = vs[c];
                Vs[r][d0 + c * 4 + 0] = g.x;
                Vs[r][d0 + c * 4 + 1] = g.y;
                Vs[r][d0 + c * 4 + 2] = g.z;
                Vs[r][d0 + c * 4 + 3] = g.w;
            }
        }
        __syncthreads();

        // ---- scores: sc[jj] = q_i . k_{jj*4+sub} ----
        float sc[16];
        #pragma unroll
        for (int jj = 0; jj < 16; ++jj) sc[jj] = 0.f;
        for (int d0 = 0; d0 < 64; d0 += 4) {
            float4 q4 = *reinterpret_cast<const float4*>(&Qs[i][d0]);
            #pragma unroll
            for (int jj = 0; jj < 16; ++jj) {
                float4 k4 = *reinterpret_cast<const float4*>(&Ks[jj * 4 + sub][d0]);
                float s = sc[jj];
                s = fmaf(q4.x, k4.x, s);
                s = fmaf(q4.y, k4.y, s);
                s = fmaf(q4.z, k4.z, s);
                s = fmaf(q4.w, k4.w, s);
                sc[jj] = s;
            }
        }

        // causal mask: only the diagonal tile needs it (finite sentinel)
        if (kt == qt) {
            #pragma unroll
            for (int jj = 0; jj < 16; ++jj)
                if (jj * 4 + sub > i) sc[jj] = NEG_BIG;
        }

        // ---- online softmax (all finite) ----
        float mx = sc[0];
        #pragma unroll
        for (int jj = 1; jj < 16; ++jj) mx = fmaxf(mx, sc[jj]);
        mx = fmaxf(mx, __shfl_xor(mx, 1));
        mx = fmaxf(mx, __shfl_xor(mx, 2));
        const float m_new = fmaxf(m, mx);
        const float alpha = __expf(m - m_new);  // first tile: exp(-3e38)=0

        float p[16];
        float ps = 0.f;
        #pragma unroll
        for (int jj = 0; jj < 16; ++jj) {
            p[jj] = __expf(sc[jj] - m_new);     // masked -> underflow to 0
            ps += p[jj];
        }
        ps += __shfl_xor(ps, 1);
        ps += __shfl_xor(ps, 2);
        l = l * alpha + ps;
        m = m_new;
        #pragma unroll
        for (int dd = 0; dd < 16; ++dd) o[dd] *= alpha;

        // ---- PV: o[dd] += sum_j p_row[j] * V[j][sub*16+dd] ----
        const int qb = lane & ~3;
        #pragma unroll
        for (int j = 0; j < 64; ++j) {
            float pv = p[j >> 2];
            float pj = __shfl(pv, qb + (j & 3));
            const float4* v0 = reinterpret_cast<const float4*>(&Vs[j][sub * 16]);
            #pragma unroll
            for (int c = 0; c < 4; ++c) {
                float4 v4 = v0[c];
                o[c * 4 + 0] = fmaf(pj, v4.x, o[c * 4 + 0]);
                o[c * 4 + 1] = fmaf(pj, v4.y, o[c * 4 + 1]);
                o[c * 4 + 2] = fmaf(pj, v4.z, o[c * 4 + 2]);
                o[c * 4 + 3] = fmaf(pj, v4.w, o[c * 4 + 3]);
            }
        }
    }

    // epilogue: normalize, write in detected dtype
    const float inv = 1.0f / l;
    const size_t ooff = batch_off + (size_t)(qbase + i) * DH + sub * 16;
    if (*flag != 0) {
        float* op = (float*)out + ooff;
        #pragma unroll
        for (int dd = 0; dd < 16; ++dd) op[dd] = o[dd] * inv;
    } else {
        __hip_bfloat16* op = (__hip_bfloat16*)out + ooff;
        #pragma unroll
        for (int dd = 0; dd < 16; ++dd) op[dd] = __float2bfloat16(o[dd] * inv);
    }
}

extern "C" void kernel_launch(void* const* d_in, const int* in_sizes, int n_in,
                              void* d_out, int out_size, void* d_ws, size_t ws_size,
                              hipStream_t stream) {
    // workspace: Q,K,V projections in fp32 — 3 * 4*4096*64*4 B = 12 MB, + flag
    float* Qw = (float*)d_ws;
    float* Kw = Qw + (size_t)B_ * S_ * DH;
    float* Vw = Kw + (size_t)B_ * S_ * DH;
    int* flag = (int*)(Vw + (size_t)B_ * S_ * DH);

    detect_kernel<<<1, 256, 0, stream>>>((const unsigned short*)d_in[0], flag);

    proj_kernel<<<dim3(B_ * S_ / TM, 3), 256, 0, stream>>>(
        d_in[0], d_in[1], d_in[2],   // xq, xk, xv
        d_in[3], d_in[5], d_in[7],   // Wq, Wk, Wv
        d_in[4], d_in[6], d_in[8],   // bq, bk, bv
        Qw, Kw, Vw, flag);

    flash_kernel<<<dim3(S_ / 64, B_), 256, 0, stream>>>(
        Qw, Kw, Vw, d_out, flag);
}

// Round 2
// 483.628 us; speedup vs baseline: 3.0971x; 1.6880x over previous
//
#include <hip/hip_runtime.h>
#include <hip/hip_bf16.h>

#define B_ 4
#define S_ 4096
#define DM 512
#define DH 64

#define NEG_BIG (-3.0e38f)

// ---------------------------------------------------------------------------
// Dtype detector: scans first 2048 uint16 halves of q_in. bf16 N(0,1) data
// has exponent fields ~[96,134]; fp32 data reinterpreted as u16 has random
// exponent fields in ~42% of halves. flag=1 -> inputs are fp32.
// ---------------------------------------------------------------------------
__global__ void detect_kernel(const unsigned short* __restrict__ u,
                              int* __restrict__ flag) {
    __shared__ int cnt;
    if (threadIdx.x == 0) cnt = 0;
    __syncthreads();
    int w = 0;
    #pragma unroll
    for (int k = 0; k < 8; ++k) {
        unsigned short x = u[threadIdx.x * 8 + k];
        int e = (x >> 7) & 0xFF;
        if (e >= 135 || (e > 0 && e <= 95)) ++w;
    }
    atomicAdd(&cnt, w);
    __syncthreads();
    if (threadIdx.x == 0) *flag = (cnt > 64) ? 1 : 0;
}

__device__ __forceinline__ float bf2f(unsigned short u) {
    unsigned int x = ((unsigned int)u) << 16;
    float f;
    __builtin_memcpy(&f, &x, 4);
    return f;
}

// ---------------------------------------------------------------------------
// Projection: tiled GEMM (64 rows x 64 heads per block, K chunked by 64).
// Unchanged from round 1.
// ---------------------------------------------------------------------------
#define TM 64
#define KC 64
#define LDX 68
#define LDW 65

__global__ __launch_bounds__(256) void proj_kernel(
    const void* __restrict__ xq, const void* __restrict__ xk,
    const void* __restrict__ xv,
    const void* __restrict__ Wq, const void* __restrict__ Wk,
    const void* __restrict__ Wv,
    const void* __restrict__ bq, const void* __restrict__ bk,
    const void* __restrict__ bv,
    float* __restrict__ Qo, float* __restrict__ Ko, float* __restrict__ Vo,
    const int* __restrict__ flag)
{
    const int which = blockIdx.y;
    const void* x    = (which == 0) ? xq : (which == 1) ? xk : xv;
    const void* W    = (which == 0) ? Wq : (which == 1) ? Wk : Wv;
    const void* bias = (which == 0) ? bq : (which == 1) ? bk : bv;
    float* out       = (which == 0) ? Qo : (which == 1) ? Ko : Vo;

    const bool f32 = (*flag != 0);
    const int row0 = blockIdx.x * TM;
    const int t    = threadIdx.x;
    const int tr   = t >> 4;
    const int tc   = t & 15;

    __shared__ float Xs[TM][LDX];
    __shared__ float Ws[KC][LDW];

    float acc[4][4];
    #pragma unroll
    for (int r = 0; r < 4; ++r)
        #pragma unroll
        for (int h = 0; h < 4; ++h) acc[r][h] = 0.f;

    for (int kc = 0; kc < DM; kc += KC) {
        __syncthreads();
        if (f32) {
            const float* xb = (const float*)x;
            #pragma unroll
            for (int jv = 0; jv < 4; ++jv) {
                int lidx = jv * 256 + t;
                int r = lidx >> 4, kq = lidx & 15;
                float4 v = *reinterpret_cast<const float4*>(
                    xb + (size_t)(row0 + r) * DM + kc + kq * 4);
                *reinterpret_cast<float4*>(&Xs[r][kq * 4]) = v;
            }
            const float* wb = (const float*)W;
            #pragma unroll
            for (int jv = 0; jv < 4; ++jv) {
                int lidx = jv * 256 + t;
                int h = lidx >> 4, kq = lidx & 15;
                float4 v = *reinterpret_cast<const float4*>(
                    wb + (size_t)h * DM + kc + kq * 4);
                Ws[kq * 4 + 0][h] = v.x;
                Ws[kq * 4 + 1][h] = v.y;
                Ws[kq * 4 + 2][h] = v.z;
                Ws[kq * 4 + 3][h] = v.w;
            }
        } else {
            const unsigned short* xb = (const unsigned short*)x;
            #pragma unroll
            for (int jv = 0; jv < 4; ++jv) {
                int lidx = jv * 256 + t;
                int r = lidx >> 4, kq = lidx & 15;
                ushort4 u = *reinterpret_cast<const ushort4*>(
                    xb + (size_t)(row0 + r) * DM + kc + kq * 4);
                Xs[r][kq * 4 + 0] = bf2f(u.x);
                Xs[r][kq * 4 + 1] = bf2f(u.y);
                Xs[r][kq * 4 + 2] = bf2f(u.z);
                Xs[r][kq * 4 + 3] = bf2f(u.w);
            }
            const unsigned short* wb = (const unsigned short*)W;
            #pragma unroll
            for (int jv = 0; jv < 4; ++jv) {
                int lidx = jv * 256 + t;
                int h = lidx >> 4, kq = lidx & 15;
                ushort4 u = *reinterpret_cast<const ushort4*>(
                    wb + (size_t)h * DM + kc + kq * 4);
                Ws[kq * 4 + 0][h] = bf2f(u.x);
                Ws[kq * 4 + 1][h] = bf2f(u.y);
                Ws[kq * 4 + 2][h] = bf2f(u.z);
                Ws[kq * 4 + 3][h] = bf2f(u.w);
            }
        }
        __syncthreads();

        #pragma unroll
        for (int k4 = 0; k4 < KC / 4; ++k4) {
            float4 xv4[4], wv4[4];
            #pragma unroll
            for (int r = 0; r < 4; ++r)
                xv4[r] = *reinterpret_cast<const float4*>(&Xs[tr * 4 + r][k4 * 4]);
            #pragma unroll
            for (int j = 0; j < 4; ++j)
                wv4[j] = *reinterpret_cast<const float4*>(&Ws[k4 * 4 + j][tc * 4]);
            #pragma unroll
            for (int r = 0; r < 4; ++r) {
                const float* xp = reinterpret_cast<const float*>(&xv4[r]);
                #pragma unroll
                for (int j = 0; j < 4; ++j) {
                    const float* wp = reinterpret_cast<const float*>(&wv4[j]);
                    float xs = xp[j];
                    #pragma unroll
                    for (int h = 0; h < 4; ++h)
                        acc[r][h] = fmaf(xs, wp[h], acc[r][h]);
                }
            }
        }
    }

    float bs[4];
    #pragma unroll
    for (int h = 0; h < 4; ++h)
        bs[h] = f32 ? ((const float*)bias)[tc * 4 + h]
                    : bf2f(((const unsigned short*)bias)[tc * 4 + h]);

    #pragma unroll
    for (int r = 0; r < 4; ++r) {
        float4 o;
        o.x = acc[r][0] + bs[0];
        o.y = acc[r][1] + bs[1];
        o.z = acc[r][2] + bs[2];
        o.w = acc[r][3] + bs[3];
        *reinterpret_cast<float4*>(
            out + (size_t)(row0 + tr * 4 + r) * DH + tc * 4) = o;
    }
}

// ---------------------------------------------------------------------------
// Flash attention v2 (causal), fp32 exact.
//  - Balanced pairing: block handles 32-row q-tiles qt=pair and qt=127-pair.
//    Every block does exactly 33 (32q x 128k) tile-units -> no tail.
//  - 4x4 register blocking in QK: thread (tr=t>>5, tc=t&31) computes rows
//    4tr..+3 x cols 4tc..+3. 8 b128 LDS reads per 64 FMA (was 17/64).
//  - K tile XOR-swizzled (d ^ ((row>>2 & 7)<<2)) so the 32-distinct-row
//    b128 reads hit the LDS bandwidth floor instead of a 16-way conflict.
//  - P staged via LDS; PV blocked 2 rows x 4 dims (rows rp, rp+16).
//  - alpha/l broadcast through a 32-float LDS array.
//  - K/V register prefetch: next tile's global loads issued during compute.
// LDS: Qs 8K + Ks 32K + Vs 32K + Ps 16.5K = 90.8 KB -> 1 block/CU (LDS pipe,
// not occupancy, is the resource).
// ---------------------------------------------------------------------------
#define LDP 132

__global__ __launch_bounds__(256, 1) void flash_kernel(
    const float* __restrict__ Q, const float* __restrict__ K,
    const float* __restrict__ V, void* __restrict__ out,
    const int* __restrict__ flag)
{
    const int pair = blockIdx.x;   // 0..63
    const int b    = blockIdx.y;   // 0..3
    const int t    = threadIdx.x;

    __shared__ float Qs[32 * 64];
    __shared__ float Ks[128 * 64];   // XOR-swizzled within each row
    __shared__ float Vs[128 * 64];   // linear
    __shared__ float Ps[32 * LDP];
    __shared__ float asx[32];

    const size_t batch_off = (size_t)b * S_ * DH;
    const bool f32o = (*flag != 0);

    // QK mapping: rows 4*(t>>5).., cols 4*(t&31)..
    const int tr  = t >> 5;
    const int r0  = tr << 2;
    const int tc  = t & 31;
    const int c0  = tc << 2;
    const int ksw = (tc & 7) << 2;       // read swizzle for rows c0..c0+3
    // PV mapping: rows rp, rp+16; dims cv0..cv0+3
    const int rp  = t >> 4;
    const int cv0 = (t & 15) << 2;
    // staging mapping: rows sr+16k, dims sd..sd+3
    const int sr = t >> 4;
    const int sd = (t & 15) << 2;

#define LOAD_TILE(kt_) do {                                                   \
        const float* kp_ = K + batch_off + ((size_t)(kt_) * 128 + sr) * 64 + sd; \
        const float* vp_ = V + batch_off + ((size_t)(kt_) * 128 + sr) * 64 + sd; \
        _Pragma("unroll")                                                     \
        for (int k = 0; k < 8; ++k) {                                         \
            kreg[k] = *reinterpret_cast<const float4*>(kp_ + (k << 10));      \
            vreg[k] = *reinterpret_cast<const float4*>(vp_ + (k << 10));      \
        } } while (0)

    #pragma unroll 1
    for (int half = 0; half < 2; ++half) {
        const int qt = half ? (127 - pair) : pair;
        const int q0 = qt << 5;
        const int nk = (qt >> 2) + 1;

        __syncthreads();   // prior q-tile's LDS reads complete
        // stage Q (pre-scaled by 1/sqrt(64))
        #pragma unroll
        for (int k = 0; k < 2; ++k) {
            int lidx = (k << 8) + t;
            int r = lidx >> 4, d0 = (lidx & 15) << 2;
            float4 f = *reinterpret_cast<const float4*>(
                Q + batch_off + (size_t)(q0 + r) * DH + d0);
            f.x *= 0.125f; f.y *= 0.125f; f.z *= 0.125f; f.w *= 0.125f;
            *reinterpret_cast<float4*>(&Qs[(r << 6) + d0]) = f;
        }

        float4 kreg[8], vreg[8];
        LOAD_TILE(0);

        float m[4], l[4], o0[4], o1[4];
        #pragma unroll
        for (int u = 0; u < 4; ++u) {
            m[u] = NEG_BIG; l[u] = 0.f; o0[u] = 0.f; o1[u] = 0.f;
        }

        for (int kt = 0; kt < nk; ++kt) {
            __syncthreads();   // prev tile's LDS reads done (also orders Qs fill)
            #pragma unroll
            for (int k = 0; k < 8; ++k) {
                int r   = (k << 4) + sr;
                int wsw = ((r >> 2) & 7) << 2;
                *reinterpret_cast<float4*>(&Ks[(r << 6) + (sd ^ wsw)]) = kreg[k];
                *reinterpret_cast<float4*>(&Vs[(r << 6) + sd]) = vreg[k];
            }
            if (kt + 1 < nk) LOAD_TILE(kt + 1);   // hide HBM/L2 latency
            __syncthreads();

            // ---- QK: sc[u][v] = q_{r0+u} . k_{c0+v} ----
            float sc[4][4];
            #pragma unroll
            for (int u = 0; u < 4; ++u)
                #pragma unroll
                for (int v = 0; v < 4; ++v) sc[u][v] = 0.f;

            #pragma unroll
            for (int d0 = 0; d0 < 64; d0 += 4) {
                float4 q4[4], k4[4];
                #pragma unroll
                for (int u = 0; u < 4; ++u)
                    q4[u] = *reinterpret_cast<const float4*>(
                        &Qs[((r0 + u) << 6) + d0]);
                #pragma unroll
                for (int v = 0; v < 4; ++v)
                    k4[v] = *reinterpret_cast<const float4*>(
                        &Ks[((c0 + v) << 6) + (d0 ^ ksw)]);
                #pragma unroll
                for (int u = 0; u < 4; ++u) {
                    #pragma unroll
                    for (int v = 0; v < 4; ++v) {
                        sc[u][v] = fmaf(q4[u].x, k4[v].x, sc[u][v]);
                        sc[u][v] = fmaf(q4[u].y, k4[v].y, sc[u][v]);
                        sc[u][v] = fmaf(q4[u].z, k4[v].z, sc[u][v]);
                        sc[u][v] = fmaf(q4[u].w, k4[v].w, sc[u][v]);
                    }
                }
            }

            // causal mask: only final k-tile. row (r0+u) allows local col
            // c <= 32*(qt&3) + r0+u.
            if (kt == nk - 1) {
                const int limbase = (qt & 3) << 5;
                #pragma unroll
                for (int u = 0; u < 4; ++u) {
                    const int lim = limbase + r0 + u;
                    #pragma unroll
                    for (int v = 0; v < 4; ++v)
                        if (c0 + v > lim) sc[u][v] = NEG_BIG;
                }
            }

            // ---- online softmax over 32-lane row groups ----
            float alpha[4];
            #pragma unroll
            for (int u = 0; u < 4; ++u) {
                float mx = fmaxf(fmaxf(sc[u][0], sc[u][1]),
                                 fmaxf(sc[u][2], sc[u][3]));
                #pragma unroll
                for (int s = 1; s < 32; s <<= 1) mx = fmaxf(mx, __shfl_xor(mx, s));
                const float mn = fmaxf(m[u], mx);
                alpha[u] = __expf(m[u] - mn);   // first tile: exp(-3e38)=0
                float ps = 0.f;
                #pragma unroll
                for (int v = 0; v < 4; ++v) {
                    sc[u][v] = __expf(sc[u][v] - mn);   // masked -> 0
                    ps += sc[u][v];
                }
                #pragma unroll
                for (int s = 1; s < 32; s <<= 1) ps += __shfl_xor(ps, s);
                l[u] = l[u] * alpha[u] + ps;
                m[u] = mn;
            }

            // stage P + alpha broadcast
            #pragma unroll
            for (int u = 0; u < 4; ++u)
                *reinterpret_cast<float4*>(&Ps[(r0 + u) * LDP + c0]) =
                    make_float4(sc[u][0], sc[u][1], sc[u][2], sc[u][3]);
            if (tc == 0) {
                #pragma unroll
                for (int u = 0; u < 4; ++u) asx[r0 + u] = alpha[u];
            }
            __syncthreads();

            // ---- PV: o[rows rp, rp+16][cv0..cv0+3] ----
            const float a0 = asx[rp], a1 = asx[rp + 16];
            #pragma unroll
            for (int v = 0; v < 4; ++v) { o0[v] *= a0; o1[v] *= a1; }

            #pragma unroll 4
            for (int j0 = 0; j0 < 128; j0 += 4) {
                float4 p0 = *reinterpret_cast<const float4*>(&Ps[rp * LDP + j0]);
                float4 p1 = *reinterpret_cast<const float4*>(&Ps[(rp + 16) * LDP + j0]);
                const float pa0[4] = {p0.x, p0.y, p0.z, p0.w};
                const float pa1[4] = {p1.x, p1.y, p1.z, p1.w};
                #pragma unroll
                for (int u = 0; u < 4; ++u) {
                    float4 vv = *reinterpret_cast<const float4*>(
                        &Vs[((j0 + u) << 6) + cv0]);
                    o0[0] = fmaf(pa0[u], vv.x, o0[0]);
                    o0[1] = fmaf(pa0[u], vv.y, o0[1]);
                    o0[2] = fmaf(pa0[u], vv.z, o0[2]);
                    o0[3] = fmaf(pa0[u], vv.w, o0[3]);
                    o1[0] = fmaf(pa1[u], vv.x, o1[0]);
                    o1[1] = fmaf(pa1[u], vv.y, o1[1]);
                    o1[2] = fmaf(pa1[u], vv.z, o1[2]);
                    o1[3] = fmaf(pa1[u], vv.w, o1[3]);
                }
            }
        }

        // ---- epilogue: broadcast l, normalize, store ----
        __syncthreads();
        if (tc == 0) {
            #pragma unroll
            for (int u = 0; u < 4; ++u) asx[r0 + u] = l[u];
        }
        __syncthreads();
        const float inv0 = 1.0f / asx[rp];
        const float inv1 = 1.0f / asx[rp + 16];
        const size_t ob0 = batch_off + (size_t)(q0 + rp) * DH + cv0;
        const size_t ob1 = batch_off + (size_t)(q0 + rp + 16) * DH + cv0;
        if (f32o) {
            float4 w0, w1;
            w0.x = o0[0] * inv0; w0.y = o0[1] * inv0;
            w0.z = o0[2] * inv0; w0.w = o0[3] * inv0;
            w1.x = o1[0] * inv1; w1.y = o1[1] * inv1;
            w1.z = o1[2] * inv1; w1.w = o1[3] * inv1;
            *reinterpret_cast<float4*>((float*)out + ob0) = w0;
            *reinterpret_cast<float4*>((float*)out + ob1) = w1;
        } else {
            __hip_bfloat16* op0 = (__hip_bfloat16*)out + ob0;
            __hip_bfloat16* op1 = (__hip_bfloat16*)out + ob1;
            #pragma unroll
            for (int v = 0; v < 4; ++v) {
                op0[v] = __float2bfloat16(o0[v] * inv0);
                op1[v] = __float2bfloat16(o1[v] * inv1);
            }
        }
    }
#undef LOAD_TILE
}

extern "C" void kernel_launch(void* const* d_in, const int* in_sizes, int n_in,
                              void* d_out, int out_size, void* d_ws, size_t ws_size,
                              hipStream_t stream) {
    // workspace: Q,K,V projections in fp32 — 3 * 4*4096*64*4 B = 12 MB, + flag
    float* Qw = (float*)d_ws;
    float* Kw = Qw + (size_t)B_ * S_ * DH;
    float* Vw = Kw + (size_t)B_ * S_ * DH;
    int* flag = (int*)(Vw + (size_t)B_ * S_ * DH);

    detect_kernel<<<1, 256, 0, stream>>>((const unsigned short*)d_in[0], flag);

    proj_kernel<<<dim3(B_ * S_ / TM, 3), 256, 0, stream>>>(
        d_in[0], d_in[1], d_in[2],   // xq, xk, xv
        d_in[3], d_in[5], d_in[7],   // Wq, Wk, Wv
        d_in[4], d_in[6], d_in[8],   // bq, bk, bv
        Qw, Kw, Vw, flag);

    flash_kernel<<<dim3(64, B_), 256, 0, stream>>>(
        Qw, Kw, Vw, d_out, flag);
}

// Round 3
// 364.350 us; speedup vs baseline: 4.1111x; 1.3274x over previous
//
#include <hip/hip_runtime.h>
#include <hip/hip_bf16.h>

#define B_ 4
#define S_ 4096
#define DM 512
#define DH 64

#define NEG_BIG (-3.0e38f)

typedef __attribute__((ext_vector_type(8))) short short8b;   // 8 bf16 (4 VGPRs)
typedef __attribute__((ext_vector_type(4))) float f32x4;     // MFMA C/D

__device__ __forceinline__ f32x4 MFMA16(short8b a, short8b b, f32x4 c) {
    return __builtin_amdgcn_mfma_f32_16x16x32_bf16(a, b, c, 0, 0, 0);
}

__device__ __forceinline__ float bf2f(unsigned short u) {
    unsigned int x = ((unsigned int)u) << 16;
    float f;
    __builtin_memcpy(&f, &x, 4);
    return f;
}
__device__ __forceinline__ unsigned short f2bf_rne(float f) {
    unsigned int u = __float_as_uint(f);
    u += 0x7FFFu + ((u >> 16) & 1u);
    return (unsigned short)(u >> 16);
}

// ---------------------------------------------------------------------------
// Dtype detector (unchanged): flag=1 -> inputs are fp32, 0 -> bf16.
// ---------------------------------------------------------------------------
__global__ void detect_kernel(const unsigned short* __restrict__ u,
                              int* __restrict__ flag) {
    __shared__ int cnt;
    if (threadIdx.x == 0) cnt = 0;
    __syncthreads();
    int w = 0;
    #pragma unroll
    for (int k = 0; k < 8; ++k) {
        unsigned short x = u[threadIdx.x * 8 + k];
        int e = (x >> 7) & 0xFF;
        if (e >= 135 || (e > 0 && e <= 95)) ++w;
    }
    atomicAdd(&cnt, w);
    __syncthreads();
    if (threadIdx.x == 0) *flag = (cnt > 64) ? 1 : 0;
}

// ---------------------------------------------------------------------------
// Projection: tiled fp32 GEMM (compute identical to round 2). NEW epilogue:
// split each output into bf16 hi + lo planes (hi = bf16(v), lo = bf16(v-hi)),
// Q pre-scaled by 1/sqrt(64), V stored TRANSPOSED as Vt[b][d][s] so flash's
// PV B-fragments are contiguous b128 reads.
// ---------------------------------------------------------------------------
#define TM 64
#define KC 64
#define LDX 68
#define LDW 65

__global__ __launch_bounds__(256) void proj_kernel(
    const void* __restrict__ xq, const void* __restrict__ xk,
    const void* __restrict__ xv,
    const void* __restrict__ Wq, const void* __restrict__ Wk,
    const void* __restrict__ Wv,
    const void* __restrict__ bq, const void* __restrict__ bk,
    const void* __restrict__ bv,
    unsigned short* __restrict__ Qhp, unsigned short* __restrict__ Qlp,
    unsigned short* __restrict__ Khp, unsigned short* __restrict__ Klp,
    unsigned short* __restrict__ Vthp, unsigned short* __restrict__ Vtlp,
    const int* __restrict__ flag)
{
    const int which = blockIdx.y;
    const void* x    = (which == 0) ? xq : (which == 1) ? xk : xv;
    const void* W    = (which == 0) ? Wq : (which == 1) ? Wk : Wv;
    const void* bias = (which == 0) ? bq : (which == 1) ? bk : bv;

    const bool f32 = (*flag != 0);
    const int row0 = blockIdx.x * TM;
    const int t    = threadIdx.x;
    const int tr   = t >> 4;
    const int tc   = t & 15;

    __shared__ float Xs[TM][LDX];
    __shared__ float Ws[KC][LDW];

    float acc[4][4];
    #pragma unroll
    for (int r = 0; r < 4; ++r)
        #pragma unroll
        for (int h = 0; h < 4; ++h) acc[r][h] = 0.f;

    for (int kc = 0; kc < DM; kc += KC) {
        __syncthreads();
        if (f32) {
            const float* xb = (const float*)x;
            #pragma unroll
            for (int jv = 0; jv < 4; ++jv) {
                int lidx = jv * 256 + t;
                int r = lidx >> 4, kq = lidx & 15;
                float4 v = *reinterpret_cast<const float4*>(
                    xb + (size_t)(row0 + r) * DM + kc + kq * 4);
                *reinterpret_cast<float4*>(&Xs[r][kq * 4]) = v;
            }
            const float* wb = (const float*)W;
            #pragma unroll
            for (int jv = 0; jv < 4; ++jv) {
                int lidx = jv * 256 + t;
                int h = lidx >> 4, kq = lidx & 15;
                float4 v = *reinterpret_cast<const float4*>(
                    wb + (size_t)h * DM + kc + kq * 4);
                Ws[kq * 4 + 0][h] = v.x;
                Ws[kq * 4 + 1][h] = v.y;
                Ws[kq * 4 + 2][h] = v.z;
                Ws[kq * 4 + 3][h] = v.w;
            }
        } else {
            const unsigned short* xb = (const unsigned short*)x;
            #pragma unroll
            for (int jv = 0; jv < 4; ++jv) {
                int lidx = jv * 256 + t;
                int r = lidx >> 4, kq = lidx & 15;
                ushort4 u = *reinterpret_cast<const ushort4*>(
                    xb + (size_t)(row0 + r) * DM + kc + kq * 4);
                Xs[r][kq * 4 + 0] = bf2f(u.x);
                Xs[r][kq * 4 + 1] = bf2f(u.y);
                Xs[r][kq * 4 + 2] = bf2f(u.z);
                Xs[r][kq * 4 + 3] = bf2f(u.w);
            }
            const unsigned short* wb = (const unsigned short*)W;
            #pragma unroll
            for (int jv = 0; jv < 4; ++jv) {
                int lidx = jv * 256 + t;
                int h = lidx >> 4, kq = lidx & 15;
                ushort4 u = *reinterpret_cast<const ushort4*>(
                    wb + (size_t)h * DM + kc + kq * 4);
                Ws[kq * 4 + 0][h] = bf2f(u.x);
                Ws[kq * 4 + 1][h] = bf2f(u.y);
                Ws[kq * 4 + 2][h] = bf2f(u.z);
                Ws[kq * 4 + 3][h] = bf2f(u.w);
            }
        }
        __syncthreads();

        #pragma unroll
        for (int k4 = 0; k4 < KC / 4; ++k4) {
            float4 xv4[4], wv4[4];
            #pragma unroll
            for (int r = 0; r < 4; ++r)
                xv4[r] = *reinterpret_cast<const float4*>(&Xs[tr * 4 + r][k4 * 4]);
            #pragma unroll
            for (int j = 0; j < 4; ++j)
                wv4[j] = *reinterpret_cast<const float4*>(&Ws[k4 * 4 + j][tc * 4]);
            #pragma unroll
            for (int r = 0; r < 4; ++r) {
                const float* xp = reinterpret_cast<const float*>(&xv4[r]);
                #pragma unroll
                for (int j = 0; j < 4; ++j) {
                    const float* wp = reinterpret_cast<const float*>(&wv4[j]);
                    float xs = xp[j];
                    #pragma unroll
                    for (int h = 0; h < 4; ++h)
                        acc[r][h] = fmaf(xs, wp[h], acc[r][h]);
                }
            }
        }
    }

    float bs[4];
    #pragma unroll
    for (int h = 0; h < 4; ++h)
        bs[h] = f32 ? ((const float*)bias)[tc * 4 + h]
                    : bf2f(((const unsigned short*)bias)[tc * 4 + h]);

    if (which < 2) {
        unsigned short* ph = (which == 0) ? Qhp : Khp;
        unsigned short* pl = (which == 0) ? Qlp : Klp;
        const float scale = (which == 0) ? 0.125f : 1.0f;   // 1/sqrt(64) folded into Q
        #pragma unroll
        for (int r = 0; r < 4; ++r) {
            ushort4 h4, l4v;
            unsigned short* hp = (unsigned short*)&h4;
            unsigned short* lp = (unsigned short*)&l4v;
            #pragma unroll
            for (int h = 0; h < 4; ++h) {
                float v = (acc[r][h] + bs[h]) * scale;
                unsigned short hb = f2bf_rne(v);
                hp[h] = hb;
                lp[h] = f2bf_rne(v - bf2f(hb));
            }
            const size_t off = (size_t)(row0 + tr * 4 + r) * DH + tc * 4;
            *reinterpret_cast<ushort4*>(ph + off) = h4;
            *reinterpret_cast<ushort4*>(pl + off) = l4v;
        }
    } else {
        const int bb = row0 >> 12;          // batch (4096 % 64 == 0)
        const int s0 = row0 & 4095;
        #pragma unroll
        for (int j = 0; j < 4; ++j) {
            ushort4 h4, l4v;
            unsigned short* hp = (unsigned short*)&h4;
            unsigned short* lp = (unsigned short*)&l4v;
            #pragma unroll
            for (int r = 0; r < 4; ++r) {
                float v = acc[r][j] + bs[j];
                unsigned short hb = f2bf_rne(v);
                hp[r] = hb;
                lp[r] = f2bf_rne(v - bf2f(hb));
            }
            const size_t off = (size_t)(bb * 64 + tc * 4 + j) * S_ + s0 + tr * 4;
            *reinterpret_cast<ushort4*>(Vthp + off) = h4;
            *reinterpret_cast<ushort4*>(Vtlp + off) = l4v;
        }
    }
}

// ---------------------------------------------------------------------------
// Flash attention v3: bf16 MFMA (16x16x32) with hi/lo split-precision.
//  - Block = 256 thr = 4 waves; q-tile 32 rows; k-tiles of 64 keys.
//    Balanced pairing (qt, 127-qt): every block does exactly 65 tile-units.
//  - Wave (qh=w&1, kh=w>>1) owns q-half x k-half (16x32) per tile:
//    QK = 3 passes (qlo*khi + qhi*klo + qhi*khi) -> fp32-grade scores.
//    PV = P(bf16) x (V_hi + V_lo), fp32 accum.
//  - Fragment addressing: A and B^T tiles both row-major [16|64][64] bf16
//    in LDS; per-lane b128 read at (row = base + l&15, bytes = ks*64+(l>>4)*16)
//    (m97-verified pattern; any K-permutation cancels between A and B).
//    C/D: col = lane&15, row = 4*(lane>>4)+reg (m89-verified).
//  - All LDS tiles XOR-swizzled: byte ^= (row&7)<<4  (Guideline 4).
//  - K/V planes register-prefetched one tile ahead.
// LDS: Q 8K + K 16K + V 16K + P 4K + stats ~0.5K = 44.5 KB.
// ---------------------------------------------------------------------------
__global__ __launch_bounds__(256, 1) void flash_kernel(
    const unsigned short* __restrict__ Qh, const unsigned short* __restrict__ Ql,
    const unsigned short* __restrict__ Kh, const unsigned short* __restrict__ Kl,
    const unsigned short* __restrict__ Vth, const unsigned short* __restrict__ Vtl,
    void* __restrict__ out, const int* __restrict__ flag)
{
    const int pair = blockIdx.x;   // 0..63
    const int b    = blockIdx.y;   // 0..3
    const int t    = threadIdx.x;
    const int lane = t & 63;
    const int w    = t >> 6;
    const int qh   = w & 1;
    const int kh   = w >> 1;
    const int l15  = lane & 15;
    const int l4   = lane >> 4;

    __shared__ __align__(16) unsigned short Qs[2][32 * 64];
    __shared__ __align__(16) unsigned short Ks[2][64 * 64];
    __shared__ __align__(16) unsigned short Vs[2][64 * 64];
    __shared__ __align__(16) unsigned short Ps[32 * 64];
    __shared__ float Mpart[2][32];
    __shared__ float Lpart[2][32];

    const int srow = t >> 3;          // 0..31
    const int sseg = t & 7;           // 0..7
    const int soff = sseg * 16;       // byte offset within 128B row

    const size_t bS = (size_t)b * S_;
    const bool f32o = (*flag != 0);

    #pragma unroll 1
    for (int half = 0; half < 2; ++half) {
        const int qt = half ? (127 - pair) : pair;
        const int q0 = qt << 5;
        const int nk = (qt >> 1) + 1;

        __syncthreads();   // prior half's LDS reads complete
        // stage Q planes (32 rows x 64 d, swizzled)
        {
            const size_t goff = (bS + q0 + srow) * 64 + sseg * 8;
            uint4 a = *reinterpret_cast<const uint4*>(Qh + goff);
            uint4 c = *reinterpret_cast<const uint4*>(Ql + goff);
            const int d = (srow << 7) + (soff ^ ((srow & 7) << 4));
            *reinterpret_cast<uint4*>((char*)&Qs[0][0] + d) = a;
            *reinterpret_cast<uint4*>((char*)&Qs[1][0] + d) = c;
        }

        uint4 rkh[2], rkl[2], rvh[2], rvl[2];
        auto load_tile = [&](int kt) {
            const int k0 = kt << 6;
            #pragma unroll
            for (int u = 0; u < 2; ++u) {
                const int rw = srow + (u << 5);
                const size_t koff = (bS + k0 + rw) * 64 + sseg * 8;
                rkh[u] = *reinterpret_cast<const uint4*>(Kh + koff);
                rkl[u] = *reinterpret_cast<const uint4*>(Kl + koff);
                const size_t voff = (size_t)(b * 64 + rw) * S_ + k0 + sseg * 8;
                rvh[u] = *reinterpret_cast<const uint4*>(Vth + voff);
                rvl[u] = *reinterpret_cast<const uint4*>(Vtl + voff);
            }
        };
        load_tile(0);

        short8b qf[2][2];          // [hilo][ks]
        f32x4 of[2];
        of[0] = f32x4{0.f, 0.f, 0.f, 0.f};
        of[1] = f32x4{0.f, 0.f, 0.f, 0.f};
        float mrun[4], lrun[4];
        #pragma unroll
        for (int r = 0; r < 4; ++r) { mrun[r] = NEG_BIG; lrun[r] = 0.f; }

        #pragma unroll 1
        for (int kt = 0; kt < nk; ++kt) {
            __syncthreads();   // prev tile's LDS reads done
            #pragma unroll
            for (int u = 0; u < 2; ++u) {
                const int rw = srow + (u << 5);
                const int d = (rw << 7) + (soff ^ ((rw & 7) << 4));
                *reinterpret_cast<uint4*>((char*)&Ks[0][0] + d) = rkh[u];
                *reinterpret_cast<uint4*>((char*)&Ks[1][0] + d) = rkl[u];
                *reinterpret_cast<uint4*>((char*)&Vs[0][0] + d) = rvh[u];
                *reinterpret_cast<uint4*>((char*)&Vs[1][0] + d) = rvl[u];
            }
            if (kt + 1 < nk) load_tile(kt + 1);   // hide global latency
            __syncthreads();

            if (kt == 0) {
                #pragma unroll
                for (int hl = 0; hl < 2; ++hl)
                    #pragma unroll
                    for (int ks = 0; ks < 2; ++ks) {
                        const int row = qh * 16 + l15;
                        const int d = (row << 7) + ((ks * 64 + l4 * 16) ^ ((row & 7) << 4));
                        qf[hl][ks] = *reinterpret_cast<const short8b*>((char*)&Qs[hl][0] + d);
                    }
            }

            // ---- QK: 3-pass split-precision MFMA ----
            f32x4 sc[2];
            #pragma unroll
            for (int ct = 0; ct < 2; ++ct) {
                f32x4 a = f32x4{0.f, 0.f, 0.f, 0.f};
                #pragma unroll
                for (int ks = 0; ks < 2; ++ks) {
                    const int brow = kh * 32 + ct * 16 + l15;
                    const int d = (brow << 7) + ((ks * 64 + l4 * 16) ^ ((brow & 7) << 4));
                    short8b bh = *reinterpret_cast<const short8b*>((char*)&Ks[0][0] + d);
                    short8b bl = *reinterpret_cast<const short8b*>((char*)&Ks[1][0] + d);
                    a = MFMA16(qf[1][ks], bh, a);   // qlo * khi
                    a = MFMA16(qf[0][ks], bl, a);   // qhi * klo
                    a = MFMA16(qf[0][ks], bh, a);   // qhi * khi
                }
                sc[ct] = a;
            }

            // causal mask: only final k-tile
            if (kt == nk - 1) {
                const int colb = (kt << 6) + kh * 32 + l15;
                const int rowb = q0 + qh * 16 + (l4 << 2);
                #pragma unroll
                for (int ct = 0; ct < 2; ++ct)
                    #pragma unroll
                    for (int r = 0; r < 4; ++r)
                        if (colb + ct * 16 > rowb + r) sc[ct][r] = NEG_BIG;
            }

            // ---- online softmax: wave-partial max -> LDS combine ----
            float pm[4];
            #pragma unroll
            for (int r = 0; r < 4; ++r) pm[r] = fmaxf(sc[0][r], sc[1][r]);
            #pragma unroll
            for (int s = 1; s < 16; s <<= 1)
                #pragma unroll
                for (int r = 0; r < 4; ++r) pm[r] = fmaxf(pm[r], __shfl_xor(pm[r], s));
            if (l15 == 0) {
                #pragma unroll
                for (int r = 0; r < 4; ++r) Mpart[kh][qh * 16 + (l4 << 2) + r] = pm[r];
            }
            __syncthreads();
            float alpha[4], mn[4];
            #pragma unroll
            for (int r = 0; r < 4; ++r) {
                float o = Mpart[kh ^ 1][qh * 16 + (l4 << 2) + r];
                mn[r] = fmaxf(mrun[r], fmaxf(pm[r], o));
                alpha[r] = __expf(mrun[r] - mn[r]);   // first tile: 0
                mrun[r] = mn[r];
            }
            float ps[4] = {0.f, 0.f, 0.f, 0.f};
            #pragma unroll
            for (int ct = 0; ct < 2; ++ct)
                #pragma unroll
                for (int r = 0; r < 4; ++r) {
                    float p = __expf(sc[ct][r] - mn[r]);   // masked -> 0
                    sc[ct][r] = p;
                    ps[r] += p;
                }
            // write P (bf16, swizzled)
            #pragma unroll
            for (int ct = 0; ct < 2; ++ct)
                #pragma unroll
                for (int r = 0; r < 4; ++r) {
                    const int row = qh * 16 + (l4 << 2) + r;
                    const int col = kh * 32 + ct * 16 + l15;
                    const int d = (row << 7) + ((col * 2) ^ ((row & 7) << 4));
                    *reinterpret_cast<unsigned short*>((char*)&Ps[0] + d) =
                        f2bf_rne(sc[ct][r]);
                }
            #pragma unroll
            for (int s = 1; s < 16; s <<= 1)
                #pragma unroll
                for (int r = 0; r < 4; ++r) ps[r] += __shfl_xor(ps[r], s);
            if (l15 == 0) {
                #pragma unroll
                for (int r = 0; r < 4; ++r) Lpart[kh][qh * 16 + (l4 << 2) + r] = ps[r];
            }
            __syncthreads();
            #pragma unroll
            for (int r = 0; r < 4; ++r) {
                float tot = ps[r] + Lpart[kh ^ 1][qh * 16 + (l4 << 2) + r];
                lrun[r] = lrun[r] * alpha[r] + tot;
            }

            // ---- rescale O, then PV ----
            #pragma unroll
            for (int ct = 0; ct < 2; ++ct)
                #pragma unroll
                for (int r = 0; r < 4; ++r) of[ct][r] *= alpha[r];

            short8b pf[2];
            #pragma unroll
            for (int ks = 0; ks < 2; ++ks) {
                const int row = qh * 16 + l15;
                const int d = (row << 7) + ((ks * 64 + l4 * 16) ^ ((row & 7) << 4));
                pf[ks] = *reinterpret_cast<const short8b*>((char*)&Ps[0] + d);
            }
            #pragma unroll
            for (int ct = 0; ct < 2; ++ct) {
                f32x4 a = of[ct];
                #pragma unroll
                for (int ks = 0; ks < 2; ++ks) {
                    const int vrow = kh * 32 + ct * 16 + l15;   // d-column index
                    const int d = (vrow << 7) + ((ks * 64 + l4 * 16) ^ ((vrow & 7) << 4));
                    short8b vh = *reinterpret_cast<const short8b*>((char*)&Vs[0][0] + d);
                    short8b vl = *reinterpret_cast<const short8b*>((char*)&Vs[1][0] + d);
                    a = MFMA16(pf[ks], vl, a);
                    a = MFMA16(pf[ks], vh, a);
                }
                of[ct] = a;
            }
        }

        // ---- epilogue: normalize + store ----
        float inv[4];
        #pragma unroll
        for (int r = 0; r < 4; ++r) inv[r] = 1.0f / lrun[r];
        #pragma unroll
        for (int ct = 0; ct < 2; ++ct) {
            const int col = kh * 32 + ct * 16 + l15;
            #pragma unroll
            for (int r = 0; r < 4; ++r) {
                const int row = q0 + qh * 16 + (l4 << 2) + r;
                const size_t idx = (bS + row) * 64 + col;
                float v = of[ct][r] * inv[r];
                if (f32o) ((float*)out)[idx] = v;
                else      ((unsigned short*)out)[idx] = f2bf_rne(v);
            }
        }
    }
}

extern "C" void kernel_launch(void* const* d_in, const int* in_sizes, int n_in,
                              void* d_out, int out_size, void* d_ws, size_t ws_size,
                              hipStream_t stream) {
    // workspace: 6 bf16 planes (Qh,Ql,Kh,Kl,Vth,Vtl) = 6 x 2MB = 12MB, + flag
    const size_t NP = (size_t)B_ * S_ * DH;
    unsigned short* Qhp  = (unsigned short*)d_ws;
    unsigned short* Qlp  = Qhp + NP;
    unsigned short* Khp  = Qhp + 2 * NP;
    unsigned short* Klp  = Qhp + 3 * NP;
    unsigned short* Vthp = Qhp + 4 * NP;
    unsigned short* Vtlp = Qhp + 5 * NP;
    int* flag = (int*)(Qhp + 6 * NP);

    detect_kernel<<<1, 256, 0, stream>>>((const unsigned short*)d_in[0], flag);

    proj_kernel<<<dim3(B_ * S_ / TM, 3), 256, 0, stream>>>(
        d_in[0], d_in[1], d_in[2],   // xq, xk, xv
        d_in[3], d_in[5], d_in[7],   // Wq, Wk, Wv
        d_in[4], d_in[6], d_in[8],   // bq, bk, bv
        Qhp, Qlp, Khp, Klp, Vthp, Vtlp, flag);

    flash_kernel<<<dim3(64, B_), 256, 0, stream>>>(
        Qhp, Qlp, Khp, Klp, Vthp, Vtlp, d_out, flag);
}